// Round 2
// baseline (550.989 us; speedup 1.0000x reference)
//
#include <hip/hip_runtime.h>
#include <hip/hip_bf16.h>

typedef unsigned long long u64;
typedef unsigned int u32;

#define NTOT   54560   // anchors per batch (r + i)
#define NMOD   27280   // anchors per modality
#define BATCH  16
#define KPAD   1024
#define MAXD   1000
#define NBIN   16384   // score-bits >> 16, max 0x3F80 (score <= 1.0)
#define BNDCAP 4096

struct Ptrs { const float* p[30]; };

// ---------------- workspace layout (all 16B aligned) ----------------
constexpr size_t SZ_KEY   = (size_t)BATCH * NTOT * 8;       // u64 keys
constexpr size_t SZ_CLS   = (size_t)BATCH * NTOT * 4;       // int class
constexpr size_t SZ_BOX   = (size_t)BATCH * NTOT * 16;      // float4 boxes
constexpr size_t SZ_TOPK  = (size_t)BATCH * KPAD * 8;       // sorted keys
constexpr size_t SZ_T4    = (size_t)BATCH * KPAD * 16;      // float4 per-topk
constexpr size_t SZ_T1    = (size_t)BATCH * KPAD * 4;       // float per-topk
constexpr size_t SZ_VAL   = (size_t)BATCH * 32 * 4;         // valid bitset
constexpr size_t SZ_CAND  = (size_t)BATCH * KPAD * 8;       // unsorted top-1000
constexpr size_t SZ_BND   = (size_t)BATCH * BNDCAP * 8;     // boundary-bin keys
constexpr size_t SZ_SEL   = (size_t)BATCH * 8;              // int2 {B1, kprime}
constexpr size_t SZ_HIST  = (size_t)BATCH * NBIN * 4;       // score histogram
constexpr size_t SZ_CNT   = (size_t)BATCH * 2 * 4;          // cntDef, cntBnd
constexpr size_t SZ_MASK  = (size_t)BATCH * KPAD * 32 * 4;  // iou mask bits

constexpr size_t OFF_KEY    = 0;
constexpr size_t OFF_CLS    = OFF_KEY   + SZ_KEY;
constexpr size_t OFF_BOX    = OFF_CLS   + SZ_CLS;
constexpr size_t OFF_TOPK   = OFF_BOX   + SZ_BOX;
constexpr size_t OFF_TRAW   = OFF_TOPK  + SZ_TOPK;
constexpr size_t OFF_TOFF   = OFF_TRAW  + SZ_T4;
constexpr size_t OFF_TAREA  = OFF_TOFF  + SZ_T4;
constexpr size_t OFF_TSCORE = OFF_TAREA + SZ_T1;
constexpr size_t OFF_TCLSF  = OFF_TSCORE+ SZ_T1;
constexpr size_t OFF_VALID  = OFF_TCLSF + SZ_T1;
constexpr size_t OFF_CAND   = OFF_VALID + SZ_VAL;
constexpr size_t OFF_BND    = OFF_CAND  + SZ_CAND;
constexpr size_t OFF_SEL    = OFF_BND   + SZ_BND;
// BIG region: hist+cnts live here early; maskG reuses the same space later
// (hist/cnts are dead by the time mask_kernel runs).
constexpr size_t OFF_BIG    = OFF_SEL   + SZ_SEL;
constexpr size_t OFF_HIST   = OFF_BIG;
constexpr size_t OFF_CNT    = OFF_HIST + SZ_HIST;
constexpr size_t OFF_MASK   = OFF_BIG;

// ---------------- kernel A: decode all anchors + score histogram ----------------
__global__ __launch_bounds__(256)
void decode_kernel(Ptrs ptrs, u64* __restrict__ keyAll, int* __restrict__ clsAll,
                   float4* __restrict__ boxAll, u32* __restrict__ hist) {
    int n = blockIdx.x * blockDim.x + threadIdx.x;
    int b = blockIdx.y;
    if (n >= NTOT) return;
    int mod = (n >= NMOD) ? 1 : 0;
    int nm = n - mod * NMOD;
    int l, pos, w, s;
    if (nm < 20480)      { l = 0; pos = nm;         w = 160; s = 8; }
    else if (nm < 25600) { l = 1; pos = nm - 20480; w = 80;  s = 16; }
    else if (nm < 26880) { l = 2; pos = nm - 25600; w = 40;  s = 32; }
    else if (nm < 27200) { l = 3; pos = nm - 26880; w = 20;  s = 64; }
    else                 { l = 4; pos = nm - 27200; w = 10;  s = 128; }
    int h = (w * 4) / 5;           // 128,64,32,16,8
    int hw = h * w;
    const float* clsP = ptrs.p[mod * 15 + l];
    const float* cntP = ptrs.p[mod * 15 + 5 + l];
    const float* regP = ptrs.p[mod * 15 + 10 + l];

    // class scores: sigmoid then max/argmax (first-index tie-break, matches jnp.argmax)
    const float* cb = clsP + (size_t)b * 20 * hw + pos;
    float best = -1.0f; int bi = 0;
    #pragma unroll
    for (int c = 0; c < 20; ++c) {
        float x = cb[(size_t)c * hw];
        float p = 1.0f / (1.0f + expf(-x));
        if (p > best) { best = p; bi = c; }
    }
    float cn = cntP[(size_t)b * hw + pos];
    float pc = 1.0f / (1.0f + expf(-cn));
    float score = sqrtf(__fmul_rn(best, pc));

    int xi = pos % w;
    int yi = pos / w;
    float cx = (float)(xi * s + (s >> 1));
    float cy = (float)(yi * s + (s >> 1));
    const float* rb = regP + (size_t)b * 4 * hw + pos;
    float r0 = rb[0], r1 = rb[(size_t)hw], r2 = rb[(size_t)2 * hw], r3 = rb[(size_t)3 * hw];
    float4 box;
    box.x = cx - r0; box.y = cy - r1; box.z = cx + r2; box.w = cy + r3;

    size_t o = (size_t)b * NTOT + n;
    u32 sbits = __float_as_uint(score);
    // distinct 48-bit composite key: descending key order == (score desc, index asc)
    keyAll[o] = ((u64)sbits << 16) | (u64)(65535 - n);
    clsAll[o] = bi + 1;
    boxAll[o] = box;
    atomicAdd(&hist[b * NBIN + (sbits >> 16)], 1u);
}

// ---------------- kernel B1: find threshold bin per batch ----------------
__global__ __launch_bounds__(1024)
void scan_kernel(const u32* __restrict__ hist, int2* __restrict__ selInfo) {
    int b = blockIdx.x, t = threadIdx.x;
    const u32* h = hist + (size_t)b * NBIN;
    // reverse order: r = 0 is bin NBIN-1 (highest score)
    u32 s = 0;
    #pragma unroll
    for (int j = 0; j < NBIN / 1024; ++j) s += h[NBIN - 1 - (t * (NBIN / 1024) + j)];
    __shared__ u32 ps[1024];
    ps[t] = s;
    __syncthreads();
    for (int off = 1; off < 1024; off <<= 1) {
        u32 v = (t >= off) ? ps[t - off] : 0u;
        __syncthreads();
        ps[t] += v;
        __syncthreads();
    }
    u32 incl = ps[t], excl = incl - s;
    if (excl < (u32)MAXD && incl >= (u32)MAXD) {
        u32 c = excl;
        for (int j = 0; j < NBIN / 1024; ++j) {
            int bin = NBIN - 1 - (t * (NBIN / 1024) + j);
            u32 hv = h[bin];
            if (c + hv >= (u32)MAXD) { selInfo[b] = make_int2(bin, (int)((u32)MAXD - c)); break; }
            c += hv;
        }
    }
}

// ---------------- kernel B2: compact definite + boundary candidates ----------------
__global__ __launch_bounds__(256)
void compact_kernel(const u64* __restrict__ keyAll, const int2* __restrict__ selInfo,
                    u32* __restrict__ cnts, u64* __restrict__ candbuf,
                    u64* __restrict__ bndbuf) {
    int n = blockIdx.x * 256 + threadIdx.x;
    int b = blockIdx.y;
    if (n >= NTOT) return;
    u64 k = keyAll[(size_t)b * NTOT + n];
    int bin = (int)(k >> 32);
    int2 si = selInfo[b];
    if (bin > si.x) {
        u32 p = atomicAdd(&cnts[b * 2 + 0], 1u);
        candbuf[(size_t)b * KPAD + p] = k;
    } else if (bin == si.x) {
        u32 p = atomicAdd(&cnts[b * 2 + 1], 1u);
        if (p < BNDCAP) bndbuf[(size_t)b * BNDCAP + p] = k;
    }
}

// ---------------- kernel B3: select k' largest from boundary bin ----------------
__global__ __launch_bounds__(256)
void bnd_select_kernel(const u64* __restrict__ bndbuf, const int2* __restrict__ selInfo,
                       u32* __restrict__ cnts, u64* __restrict__ candbuf) {
    int b = blockIdx.x, tid = threadIdx.x;
    int C = min((int)cnts[b * 2 + 1], BNDCAP);
    int kp = selInfo[b].y;
    __shared__ u64 sk[BNDCAP];
    for (int i = tid; i < C; i += 256) sk[i] = bndbuf[(size_t)b * BNDCAP + i];
    __syncthreads();
    for (int i = tid; i < C; i += 256) {
        u64 ki = sk[i];
        int rank = 0;
        for (int j = 0; j < C; ++j) rank += (sk[j] > ki) ? 1 : 0;
        if (rank < kp) {
            u32 p = atomicAdd(&cnts[b * 2 + 0], 1u);
            candbuf[(size_t)b * KPAD + p] = ki;
        }
    }
}

// ---------------- kernel B4: rank-sort the exact 1000 into descending order ----------------
__global__ __launch_bounds__(256)
void ranksort_kernel(const u64* __restrict__ candbuf, u64* __restrict__ topkey) {
    int b = blockIdx.y, tid = threadIdx.x;
    __shared__ u64 sk[MAXD];
    for (int t = tid; t < MAXD; t += 256) sk[t] = candbuf[(size_t)b * KPAD + t];
    __syncthreads();
    int i = blockIdx.x * 256 + tid;
    if (i < MAXD) {
        u64 ki = sk[i];
        int rank = 0;
        for (int j = 0; j < MAXD; ++j) rank += (sk[j] > ki) ? 1 : 0;
        topkey[(size_t)b * KPAD + rank] = ki;   // keys distinct -> bijection
    }
}

// ---------------- kernel C1: gather top-k, maxc, class-offset boxes, areas ----------------
__global__ __launch_bounds__(256)
void gather_kernel(const u64* __restrict__ topkey, const int* __restrict__ clsAll,
                   const float4* __restrict__ boxAll,
                   float4* __restrict__ traw, float4* __restrict__ toff,
                   float* __restrict__ tarea, float* __restrict__ tscore,
                   float* __restrict__ tclsf, u32* __restrict__ validbits) {
    #pragma clang fp contract(off)
    int b = blockIdx.x, tid = threadIdx.x;
    __shared__ float red[256];
    __shared__ u32 vb[32];
    __shared__ float s_maxc;
    if (tid < 32) vb[tid] = 0;
    __syncthreads();
    float lmax = -INFINITY;
    float4 raw[4]; float sc[4]; float cf[4];
    #pragma unroll
    for (int it = 0; it < 4; ++it) {
        int s2 = tid + it * 256;
        float4 bx = make_float4(0.f, 0.f, 0.f, 0.f);
        float score = 0.f, clsf = 0.f;
        if (s2 < MAXD) {
            u64 key = topkey[(size_t)b * KPAD + s2];
            int n = 65535 - (int)(key & 0xFFFFull);
            score = __uint_as_float((u32)(key >> 16));
            bx = boxAll[(size_t)b * NTOT + n];
            clsf = (float)clsAll[(size_t)b * NTOT + n];
            int valid = (score >= 0.05f) ? 1 : 0;
            float contrib = valid ? fmaxf(fmaxf(bx.x, bx.y), fmaxf(bx.z, bx.w)) : 0.0f;
            lmax = fmaxf(lmax, contrib);
            if (valid) atomicOr(&vb[s2 >> 5], 1u << (s2 & 31));
        }
        raw[it] = bx; sc[it] = score; cf[it] = clsf;
    }
    red[tid] = lmax;
    __syncthreads();
    for (int st = 128; st > 0; st >>= 1) {
        if (tid < st) red[tid] = fmaxf(red[tid], red[tid + st]);
        __syncthreads();
    }
    if (tid == 0) s_maxc = red[0];
    __syncthreads();
    float m1 = s_maxc + 1.0f;
    #pragma unroll
    for (int it = 0; it < 4; ++it) {
        int s2 = tid + it * 256;
        float4 bx = raw[it];
        float o = __fmul_rn(cf[it], m1);
        float4 ob;
        ob.x = __fadd_rn(bx.x, o); ob.y = __fadd_rn(bx.y, o);
        ob.z = __fadd_rn(bx.z, o); ob.w = __fadd_rn(bx.w, o);
        float dw = ob.z - ob.x + 1.0f;
        float dh = ob.w - ob.y + 1.0f;
        float area = __fmul_rn(dw, dh);
        size_t oo = (size_t)b * KPAD + s2;
        traw[oo] = bx; toff[oo] = ob; tarea[oo] = area;
        tscore[oo] = sc[it]; tclsf[oo] = cf[it];
    }
    if (tid < 32) validbits[b * 32 + tid] = vb[tid];
}

// ---------------- kernel C2: IoU > 0.6 suppression bitmask ----------------
__global__ __launch_bounds__(256)
void mask_kernel(const float4* __restrict__ toff, const float* __restrict__ tarea,
                 u32* __restrict__ maskG) {
    #pragma clang fp contract(off)
    int b = blockIdx.y;
    int i0 = blockIdx.x * 8;
    int tid = threadIdx.x;
    __shared__ float sx1[KPAD], sy1[KPAD], sx2[KPAD], sy2[KPAD], sa[KPAD];
    for (int t = tid; t < KPAD; t += 256) {
        float4 f = toff[(size_t)b * KPAD + t];
        sx1[t] = f.x; sy1[t] = f.y; sx2[t] = f.z; sy2[t] = f.w;
        sa[t] = tarea[(size_t)b * KPAD + t];
    }
    __syncthreads();
    int i = i0 + (tid >> 5);
    int w = tid & 31;
    float x1i = sx1[i], y1i = sy1[i], x2i = sx2[i], y2i = sy2[i], ai = sa[i];
    u32 bits = 0;
    for (int jj = 0; jj < 32; ++jj) {
        int j = w * 32 + jj;
        float iw = fminf(x2i, sx2[j]) - fmaxf(x1i, sx1[j]) + 1.0f;
        iw = fmaxf(iw, 0.0f);
        float ih = fminf(y2i, sy2[j]) - fmaxf(y1i, sy1[j]) + 1.0f;
        ih = fmaxf(ih, 0.0f);
        float inter = iw * ih;
        float denom = (ai + sa[j]) - inter;
        float iou = inter / denom;
        bits |= (iou > 0.6f) ? (1u << jj) : 0u;
    }
    maskG[((size_t)b * KPAD + i) * 32 + w] = bits;
}

// ---------------- kernel C3: sequential greedy scan (1 wave / batch) + outputs ----------------
__global__ __launch_bounds__(64)
void scan_out_kernel(const u32* __restrict__ maskG, const u32* __restrict__ validbits,
                     const float4* __restrict__ traw, const float* __restrict__ tscore,
                     const float* __restrict__ tclsf, float* __restrict__ out) {
    int b = blockIdx.x;
    int lane = threadIdx.x;
    int lw = lane & 31;
    const u32* mrow = maskG + (size_t)b * KPAD * 32;
    u32 vreg = (lane < 32) ? validbits[b * 32 + lane] : 0u;
    u32 removed = 0u, keepw = 0u;
    u32 m[8];
    #pragma unroll
    for (int d = 0; d < 8; ++d) m[d] = mrow[d * 32 + lw];
    for (int t = 0; t < 125; ++t) {
        #pragma unroll
        for (int d = 0; d < 8; ++d) {
            int i = t * 8 + d;
            int wi = i >> 5, bi2 = i & 31;
            u32 rw = (u32)__builtin_amdgcn_readlane((int)removed, wi);
            u32 vw = (u32)__builtin_amdgcn_readlane((int)vreg, wi);
            u32 k = ((vw >> bi2) & 1u) & (~(rw >> bi2) & 1u);
            if (k) removed |= m[d];
            if (lane == wi) keepw |= (k << bi2);
            m[d] = mrow[(size_t)(i + 8) * 32 + lw];   // prefetch (rows up to 1007 exist)
        }
    }
    __shared__ u32 keeps[32];
    if (lane < 32) keeps[lane] = keepw;
    __syncthreads();
    const int BQ = BATCH * MAXD;
    for (int s2 = lane; s2 < MAXD; s2 += 64) {
        u32 kf = (keeps[s2 >> 5] >> (s2 & 31)) & 1u;
        size_t oo = (size_t)b * KPAD + s2;
        float score = tscore[oo];
        float clsf = tclsf[oo];
        float4 bx = traw[oo];
        float x1 = fminf(fmaxf(bx.x, 0.f), 1279.f);
        float y1 = fminf(fmaxf(bx.y, 0.f), 1023.f);
        float x2 = fminf(fmaxf(bx.z, 0.f), 1279.f);
        float y2 = fminf(fmaxf(bx.w, 0.f), 1023.f);
        int base = b * MAXD + s2;
        out[base] = kf ? score : 0.0f;
        out[BQ + base] = kf ? clsf : 0.0f;
        float* ob = out + 2 * BQ + (size_t)base * 4;
        ob[0] = kf ? x1 : 0.f; ob[1] = kf ? y1 : 0.f;
        ob[2] = kf ? x2 : 0.f; ob[3] = kf ? y2 : 0.f;
        out[6 * BQ + base] = kf ? 1.0f : 0.0f;
    }
}

// ---------------- launch ----------------
extern "C" void kernel_launch(void* const* d_in, const int* in_sizes, int n_in,
                              void* d_out, int out_size, void* d_ws, size_t ws_size,
                              hipStream_t stream) {
    Ptrs ptrs;
    for (int i = 0; i < 30; ++i) ptrs.p[i] = (const float*)d_in[i];

    char* ws = (char*)d_ws;
    u64*    keyAll    = (u64*)   (ws + OFF_KEY);
    int*    clsAll    = (int*)   (ws + OFF_CLS);
    float4* boxAll    = (float4*)(ws + OFF_BOX);
    u64*    topkey    = (u64*)   (ws + OFF_TOPK);
    float4* traw      = (float4*)(ws + OFF_TRAW);
    float4* toff      = (float4*)(ws + OFF_TOFF);
    float*  tarea     = (float*) (ws + OFF_TAREA);
    float*  tscore    = (float*) (ws + OFF_TSCORE);
    float*  tclsf     = (float*) (ws + OFF_TCLSF);
    u32*    validbits = (u32*)   (ws + OFF_VALID);
    u64*    candbuf   = (u64*)   (ws + OFF_CAND);
    u64*    bndbuf    = (u64*)   (ws + OFF_BND);
    int2*   selInfo   = (int2*)  (ws + OFF_SEL);
    u32*    hist      = (u32*)   (ws + OFF_HIST);
    u32*    cnts      = (u32*)   (ws + OFF_CNT);
    u32*    maskG     = (u32*)   (ws + OFF_MASK);
    float*  out       = (float*)d_out;

    hipMemsetAsync(ws + OFF_HIST, 0, SZ_HIST + SZ_CNT, stream);

    dim3 gA((NTOT + 255) / 256, BATCH);
    decode_kernel<<<gA, 256, 0, stream>>>(ptrs, keyAll, clsAll, boxAll, hist);
    scan_kernel<<<BATCH, 1024, 0, stream>>>(hist, selInfo);
    compact_kernel<<<gA, 256, 0, stream>>>(keyAll, selInfo, cnts, candbuf, bndbuf);
    bnd_select_kernel<<<BATCH, 256, 0, stream>>>(bndbuf, selInfo, cnts, candbuf);
    ranksort_kernel<<<dim3((MAXD + 255) / 256, BATCH), 256, 0, stream>>>(candbuf, topkey);
    gather_kernel<<<BATCH, 256, 0, stream>>>(topkey, clsAll, boxAll, traw, toff,
                                             tarea, tscore, tclsf, validbits);
    mask_kernel<<<dim3(KPAD / 8, BATCH), 256, 0, stream>>>(toff, tarea, maskG);
    scan_out_kernel<<<BATCH, 64, 0, stream>>>(maskG, validbits, traw, tscore, tclsf, out);
}

// Round 3
// 417.289 us; speedup vs baseline: 1.3204x; 1.3204x over previous
//
#include <hip/hip_runtime.h>
#include <hip/hip_bf16.h>

typedef unsigned long long u64;
typedef unsigned int u32;

#define NTOT    54560   // anchors per batch (r + i)
#define NMOD    27280   // anchors per modality
#define BATCH   16
#define KPAD    1024
#define MAXD    1000
#define NBIN    16384   // score-bits >> 16 (score <= 1.0 -> bin <= 0x3F80)
#define CANDCAP 6144

struct Ptrs { const float* p[30]; };

// ---------------- workspace layout (16B aligned) ----------------
constexpr size_t SZ_KEY   = (size_t)BATCH * NTOT * 8;
constexpr size_t SZ_TOPK  = (size_t)BATCH * KPAD * 8;
constexpr size_t SZ_T4    = (size_t)BATCH * KPAD * 16;
constexpr size_t SZ_T1    = (size_t)BATCH * KPAD * 4;
constexpr size_t SZ_VAL   = (size_t)BATCH * 32 * 4;
constexpr size_t SZ_HIST  = (size_t)BATCH * NBIN * 4;      // 1 MB
constexpr size_t SZ_MASK  = (size_t)BATCH * KPAD * 32 * 4; // 2 MB

constexpr size_t OFF_KEY    = 0;
constexpr size_t OFF_TOPK   = OFF_KEY   + SZ_KEY;
constexpr size_t OFF_TRAW   = OFF_TOPK  + SZ_TOPK;
constexpr size_t OFF_TOFF   = OFF_TRAW  + SZ_T4;
constexpr size_t OFF_TAREA  = OFF_TOFF  + SZ_T4;
constexpr size_t OFF_TSCORE = OFF_TAREA + SZ_T1;
constexpr size_t OFF_TCLSF  = OFF_TSCORE+ SZ_T1;
constexpr size_t OFF_VALID  = OFF_TCLSF + SZ_T1;
// hist is dead after select_kernel; maskG reuses the space.
constexpr size_t OFF_BIG    = OFF_VALID + SZ_VAL;
constexpr size_t OFF_HIST   = OFF_BIG;
constexpr size_t OFF_MASK   = OFF_BIG;

__device__ inline void level_of(int nm, int& l, int& pos, int& w, int& s, int& hw) {
    if (nm < 20480)      { l = 0; pos = nm;         w = 160; s = 8;   hw = 20480; }
    else if (nm < 25600) { l = 1; pos = nm - 20480; w = 80;  s = 16;  hw = 5120; }
    else if (nm < 26880) { l = 2; pos = nm - 25600; w = 40;  s = 32;  hw = 1280; }
    else if (nm < 27200) { l = 3; pos = nm - 26880; w = 20;  s = 64;  hw = 320; }
    else                 { l = 4; pos = nm - 27200; w = 10;  s = 128; hw = 80; }
}

__device__ inline float sigm(float x) { return 1.0f / (1.0f + expf(-x)); }

// ---------------- kernel 1: decode scores -> keys + histogram ----------------
// 1 thread = 4 consecutive anchors (level sizes all divisible by 4 -> never straddles).
// max over raw logits, ONE sigmoid: bitwise == max(sigmoid(x)) by monotonicity.
__global__ __launch_bounds__(256)
void decode_kernel(Ptrs ptrs, ulonglong2* __restrict__ keyAll2, u32* __restrict__ hist) {
    int t = blockIdx.x * 256 + threadIdx.x;
    int b = blockIdx.y;
    if (t >= NTOT / 4) return;
    int n0 = t * 4;
    int mod = (n0 >= NMOD) ? 1 : 0;
    int nm = n0 - mod * NMOD;
    int l, pos, w, s, hw;
    level_of(nm, l, pos, w, s, hw);
    (void)w; (void)s;
    const float* clsP = ptrs.p[mod * 15 + l];
    const float* cntP = ptrs.p[mod * 15 + 5 + l];

    const float4* cb = (const float4*)(clsP + (size_t)b * 20 * hw + pos);
    int hw4 = hw >> 2;
    float4 mx = cb[0];
    #pragma unroll
    for (int c = 1; c < 20; ++c) {
        float4 v = cb[(size_t)c * hw4];
        mx.x = fmaxf(mx.x, v.x); mx.y = fmaxf(mx.y, v.y);
        mx.z = fmaxf(mx.z, v.z); mx.w = fmaxf(mx.w, v.w);
    }
    float4 cv = *(const float4*)(cntP + (size_t)b * hw + pos);

    float mxa[4] = {mx.x, mx.y, mx.z, mx.w};
    float cva[4] = {cv.x, cv.y, cv.z, cv.w};
    u32 sb[4];
    #pragma unroll
    for (int a = 0; a < 4; ++a) {
        float pb = sigm(mxa[a]);
        float pc = sigm(cva[a]);
        sb[a] = __float_as_uint(sqrtf(__fmul_rn(pb, pc)));
    }
    // distinct 48-bit key: descending order == (score desc, index asc)
    ulonglong2 k01, k23;
    k01.x = ((u64)sb[0] << 16) | (u64)(65535 - (n0 + 0));
    k01.y = ((u64)sb[1] << 16) | (u64)(65535 - (n0 + 1));
    k23.x = ((u64)sb[2] << 16) | (u64)(65535 - (n0 + 2));
    k23.y = ((u64)sb[3] << 16) | (u64)(65535 - (n0 + 3));
    size_t o2 = ((size_t)b * NTOT + n0) >> 1;
    keyAll2[o2]     = k01;
    keyAll2[o2 + 1] = k23;

    u32* hb = hist + (size_t)b * NBIN;
    #pragma unroll
    for (int a = 0; a < 4; ++a) atomicAdd(&hb[sb[a] >> 16], 1u);
}

// ---------------- kernel 2: per-batch exact top-1000 (hist scan + compact + rank sort) ----------------
__global__ __launch_bounds__(1024)
void select_kernel(const u64* __restrict__ keyAll, const u32* __restrict__ hist,
                   u64* __restrict__ topkey) {
    int b = blockIdx.x, tid = threadIdx.x;
    __shared__ u32 ps[1024];
    __shared__ int sB1;
    __shared__ u32 s_cnt;
    __shared__ u64 sk[CANDCAP];   // 48 KB
    const u32* h = hist + (size_t)b * NBIN;

    // phase 1: reverse cumulative histogram -> bin of the 1000th-largest key
    u32 loc[16]; u32 sum = 0;
    #pragma unroll
    for (int j = 0; j < 16; ++j) { loc[j] = h[NBIN - 1 - (tid * 16 + j)]; sum += loc[j]; }
    if (tid == 0) s_cnt = 0;
    ps[tid] = sum;
    __syncthreads();
    for (int off = 1; off < 1024; off <<= 1) {
        u32 v = (tid >= off) ? ps[tid - off] : 0u;
        __syncthreads();
        ps[tid] += v;
        __syncthreads();
    }
    u32 incl = ps[tid], excl = incl - sum;
    if (excl < (u32)MAXD && incl >= (u32)MAXD) {
        u32 c = excl;
        #pragma unroll
        for (int j = 0; j < 16; ++j) {
            c += loc[j];
            if (c >= (u32)MAXD) { sB1 = NBIN - 1 - (tid * 16 + j); break; }
        }
    }
    __syncthreads();
    int B1 = sB1;

    // phase 2: compact all keys with bin >= B1 (superset of top-1000) into LDS
    const u64* keys = keyAll + (size_t)b * NTOT;
    for (int n = tid; n < NTOT; n += 1024) {
        u64 k = keys[n];
        if ((int)(k >> 32) >= B1) {
            u32 p = atomicAdd(&s_cnt, 1u);
            if (p < CANDCAP) sk[p] = k;
        }
    }
    __syncthreads();
    int C = min((int)s_cnt, CANDCAP);

    // phase 3: rank-sort; candidate rank == global rank (all non-candidates are smaller)
    for (int i = tid; i < C; i += 1024) {
        u64 ki = sk[i];
        int rank = 0;
        for (int j = 0; j < C; ++j) rank += (sk[j] > ki) ? 1 : 0;
        if (rank < MAXD) topkey[(size_t)b * KPAD + rank] = ki;
    }
}

// ---------------- kernel 3: gather winners -> class/box/maxc/offset boxes ----------------
__global__ __launch_bounds__(1024)
void gather_kernel(Ptrs ptrs, const u64* __restrict__ topkey,
                   float4* __restrict__ traw, float4* __restrict__ toff,
                   float* __restrict__ tarea, float* __restrict__ tscore,
                   float* __restrict__ tclsf, u32* __restrict__ validbits) {
    #pragma clang fp contract(off)
    int b = blockIdx.x, tid = threadIdx.x;
    __shared__ float red[1024];
    __shared__ u32 vb[32];
    __shared__ float s_maxc;
    if (tid < 32) vb[tid] = 0;
    __syncthreads();

    float4 bx = make_float4(0.f, 0.f, 0.f, 0.f);
    float score = 0.f, clsf = 0.f;
    if (tid < MAXD) {
        u64 key = topkey[(size_t)b * KPAD + tid];
        int n = 65535 - (int)(key & 0xFFFFull);
        score = __uint_as_float((u32)(key >> 16));
        int mod = (n >= NMOD) ? 1 : 0;
        int nm = n - mod * NMOD;
        int l, pos, w, s, hw;
        level_of(nm, l, pos, w, s, hw);
        const float* clsP = ptrs.p[mod * 15 + l];
        const float* regP = ptrs.p[mod * 15 + 10 + l];
        const float* cbp = clsP + (size_t)b * 20 * hw + pos;
        float best = -1.0f; int bi = 0;
        #pragma unroll
        for (int c = 0; c < 20; ++c) {
            float p = sigm(cbp[(size_t)c * hw]);
            if (p > best) { best = p; bi = c; }
        }
        clsf = (float)(bi + 1);
        int xi = pos % w, yi = pos / w;
        float cx = (float)(xi * s + (s >> 1));
        float cy = (float)(yi * s + (s >> 1));
        const float* rb = regP + (size_t)b * 4 * hw + pos;
        bx.x = cx - rb[0];
        bx.y = cy - rb[(size_t)hw];
        bx.z = cx + rb[(size_t)2 * hw];
        bx.w = cy + rb[(size_t)3 * hw];
    }
    int valid = (tid < MAXD) && (score >= 0.05f);
    float contrib = (tid < MAXD)
        ? (valid ? fmaxf(fmaxf(bx.x, bx.y), fmaxf(bx.z, bx.w)) : 0.0f)
        : -INFINITY;
    if (valid) atomicOr(&vb[tid >> 5], 1u << (tid & 31));
    red[tid] = contrib;
    __syncthreads();
    for (int st = 512; st > 0; st >>= 1) {
        if (tid < st) red[tid] = fmaxf(red[tid], red[tid + st]);
        __syncthreads();
    }
    if (tid == 0) s_maxc = red[0];
    __syncthreads();

    float m1 = s_maxc + 1.0f;
    float o = __fmul_rn(clsf, m1);
    float4 ob;
    ob.x = __fadd_rn(bx.x, o); ob.y = __fadd_rn(bx.y, o);
    ob.z = __fadd_rn(bx.z, o); ob.w = __fadd_rn(bx.w, o);
    float dw = ob.z - ob.x + 1.0f;
    float dh = ob.w - ob.y + 1.0f;
    size_t oo = (size_t)b * KPAD + tid;
    traw[oo] = bx; toff[oo] = ob; tarea[oo] = __fmul_rn(dw, dh);
    tscore[oo] = score; tclsf[oo] = clsf;
    if (tid < 32) validbits[b * 32 + tid] = vb[tid];
}

// ---------------- kernel 4: IoU>0.6 bitmask, upper-triangle units ----------------
// unit = 8 rows x 256 cols. Units with all j < i0 are skipped entirely; their
// words are never read usefully by the scan (bit j only consumed at step j).
#define SW(t) ((((t) & 31) << 3) | ((t) >> 5))   // LDS swizzle: kills stride-32 bank conflict
__global__ __launch_bounds__(64)
void mask_kernel(const float4* __restrict__ toff, const float* __restrict__ tarea,
                 u32* __restrict__ maskG) {
    #pragma clang fp contract(off)
    int u = blockIdx.x, b = blockIdx.y, tid = threadIdx.x;
    int g, wg;
    if (u < 128)      { g = u >> 2;                 wg = u & 3; }
    else if (u < 224) { int i2 = u - 128; g = 32 + i2 / 3;      wg = 1 + i2 % 3; }
    else if (u < 288) { int i2 = u - 224; g = 64 + (i2 >> 1);   wg = 2 + (i2 & 1); }
    else              { g = 96 + (u - 288);         wg = 3; }
    int i0 = g * 8, j0 = wg * 256;

    __shared__ float cx1[256], cy1[256], cx2[256], cy2[256], ca[256];
    for (int t = tid; t < 256; t += 64) {
        float4 f = toff[(size_t)b * KPAD + j0 + t];
        int ts = SW(t);
        cx1[ts] = f.x; cy1[ts] = f.y; cx2[ts] = f.z; cy2[ts] = f.w;
        ca[ts] = tarea[(size_t)b * KPAD + j0 + t];
    }
    __syncthreads();

    int ir = tid >> 3, wr = tid & 7;
    int i = i0 + ir;
    float4 fi = toff[(size_t)b * KPAD + i];
    float ai = tarea[(size_t)b * KPAD + i];
    u32 bits = 0;
    int jb = wr * 32;
    for (int jj = 0; jj < 32; ++jj) {
        int js = SW(jb + jj);
        float iw = fminf(fi.z, cx2[js]) - fmaxf(fi.x, cx1[js]) + 1.0f;
        iw = fmaxf(iw, 0.0f);
        float ih = fminf(fi.w, cy2[js]) - fmaxf(fi.y, cy1[js]) + 1.0f;
        ih = fmaxf(ih, 0.0f);
        float inter = iw * ih;
        float denom = (ai + ca[js]) - inter;
        float iou = inter / denom;
        bits |= (iou > 0.6f) ? (1u << jj) : 0u;
    }
    maskG[((size_t)b * KPAD + i) * 32 + wg * 8 + wr] = bits;
}

// ---------------- kernel 5: greedy scan (1 wave/batch, depth-16 prefetch) + outputs ----------------
__global__ __launch_bounds__(64)
void scan_out_kernel(const u32* __restrict__ maskG, const u32* __restrict__ validbits,
                     const float4* __restrict__ traw, const float* __restrict__ tscore,
                     const float* __restrict__ tclsf, float* __restrict__ out) {
    int b = blockIdx.x, lane = threadIdx.x;
    int lw = lane & 31;
    const u32* mrow = maskG + (size_t)b * KPAD * 32;
    u32 vreg = (lane < 32) ? validbits[b * 32 + lane] : 0u;
    u32 removed = 0u, keepw = 0u;
    u32 mA[8], mB[8];
    #pragma unroll
    for (int d = 0; d < 8; ++d) {
        mA[d] = mrow[(size_t)d * 32 + lw];
        mB[d] = mrow[(size_t)(d + 8) * 32 + lw];
    }
    auto step8 = [&](int base, u32* ms) {
        #pragma unroll
        for (int d = 0; d < 8; ++d) {
            int i = base + d;
            int wi = i >> 5, bi2 = i & 31;
            u32 rw = (u32)__builtin_amdgcn_readlane((int)removed, wi);
            u32 vw = (u32)__builtin_amdgcn_readlane((int)vreg, wi);
            u32 k = ((vw >> bi2) & 1u) & (~(rw >> bi2) & 1u);
            if (k) removed |= ms[d];
            if (lane == wi) keepw |= (k << bi2);
            ms[d] = mrow[(size_t)(i + 16) * 32 + lw];   // rows <= 1015 exist in buffer
        }
    };
    for (int t = 0; t < 62; ++t) { step8(t * 16, mA); step8(t * 16 + 8, mB); }
    step8(992, mA);   // steps 992..999

    __shared__ u32 keeps[32];
    if (lane < 32) keeps[lane] = keepw;
    __syncthreads();
    const int BQ = BATCH * MAXD;
    for (int s2 = lane; s2 < MAXD; s2 += 64) {
        u32 kf = (keeps[s2 >> 5] >> (s2 & 31)) & 1u;
        size_t oo = (size_t)b * KPAD + s2;
        float score = tscore[oo];
        float clsf = tclsf[oo];
        float4 bx = traw[oo];
        float x1 = fminf(fmaxf(bx.x, 0.f), 1279.f);
        float y1 = fminf(fmaxf(bx.y, 0.f), 1023.f);
        float x2 = fminf(fmaxf(bx.z, 0.f), 1279.f);
        float y2 = fminf(fmaxf(bx.w, 0.f), 1023.f);
        int base = b * MAXD + s2;
        out[base] = kf ? score : 0.0f;
        out[BQ + base] = kf ? clsf : 0.0f;
        float* ob = out + 2 * BQ + (size_t)base * 4;
        ob[0] = kf ? x1 : 0.f; ob[1] = kf ? y1 : 0.f;
        ob[2] = kf ? x2 : 0.f; ob[3] = kf ? y2 : 0.f;
        out[6 * BQ + base] = kf ? 1.0f : 0.0f;
    }
}

// ---------------- launch ----------------
extern "C" void kernel_launch(void* const* d_in, const int* in_sizes, int n_in,
                              void* d_out, int out_size, void* d_ws, size_t ws_size,
                              hipStream_t stream) {
    Ptrs ptrs;
    for (int i = 0; i < 30; ++i) ptrs.p[i] = (const float*)d_in[i];

    char* ws = (char*)d_ws;
    u64*        keyAll    = (u64*)       (ws + OFF_KEY);
    ulonglong2* keyAll2   = (ulonglong2*)(ws + OFF_KEY);
    u64*        topkey    = (u64*)       (ws + OFF_TOPK);
    float4*     traw      = (float4*)    (ws + OFF_TRAW);
    float4*     toff      = (float4*)    (ws + OFF_TOFF);
    float*      tarea     = (float*)     (ws + OFF_TAREA);
    float*      tscore    = (float*)     (ws + OFF_TSCORE);
    float*      tclsf     = (float*)     (ws + OFF_TCLSF);
    u32*        validbits = (u32*)       (ws + OFF_VALID);
    u32*        hist      = (u32*)       (ws + OFF_HIST);
    u32*        maskG     = (u32*)       (ws + OFF_MASK);
    float*      out       = (float*)d_out;

    hipMemsetAsync(ws + OFF_HIST, 0, SZ_HIST, stream);
    decode_kernel<<<dim3((NTOT / 4 + 255) / 256, BATCH), 256, 0, stream>>>(ptrs, keyAll2, hist);
    select_kernel<<<BATCH, 1024, 0, stream>>>(keyAll, hist, topkey);
    gather_kernel<<<BATCH, 1024, 0, stream>>>(ptrs, topkey, traw, toff, tarea,
                                              tscore, tclsf, validbits);
    mask_kernel<<<dim3(320, BATCH), 64, 0, stream>>>(toff, tarea, maskG);
    scan_out_kernel<<<BATCH, 64, 0, stream>>>(maskG, validbits, traw, tscore, tclsf, out);
}